// Round 8
// baseline (190.880 us; speedup 1.0000x reference)
//
#include <hip/hip_runtime.h>

// B=4, T=2048, C=1024, H=16, D=64.  M = B*T = 8192.
// cast f32->bf16; 256x256 8-phase QKV GEMM; V transpose; 4-wave 64q/wave 32x32
// swapped-operand causal flash attention (2 q-sets share K/V LDS reads); 8-phase out GEMM.

typedef __attribute__((ext_vector_type(8))) __bf16 bf16x8;
typedef __attribute__((ext_vector_type(4))) float f32x4;
typedef __attribute__((ext_vector_type(16))) float f32x16;

__device__ __forceinline__ unsigned short f2bf(float f) {
  union { float f; unsigned u; } v; v.f = f;
  unsigned r = v.u + 0x7fffu + ((v.u >> 16) & 1u);   // RNE
  return (unsigned short)(r >> 16);
}

__device__ __forceinline__ unsigned cvtpk(float lo, float hi) {
  unsigned r;
  asm("v_cvt_pk_bf16_f32 %0, %1, %2" : "=v"(r) : "v"(lo), "v"(hi));
  return r;
}

__device__ __forceinline__ void gld16(const void* g, void* l) {
  __builtin_amdgcn_global_load_lds(
      (const __attribute__((address_space(1))) void*)g,
      (__attribute__((address_space(3))) void*)l, 16, 0, 0);
}

__device__ __forceinline__ f32x4 mfma16(bf16x8 a, bf16x8 b, f32x4 c) {
  return __builtin_amdgcn_mfma_f32_16x16x32_bf16(a, b, c, 0, 0, 0);
}
__device__ __forceinline__ f32x16 mfma32(bf16x8 a, bf16x8 b, f32x16 c) {
  return __builtin_amdgcn_mfma_f32_32x32x16_bf16(a, b, c, 0, 0, 0);
}

__global__ __launch_bounds__(256) void cast_f32_bf16(
    const float* __restrict__ src, unsigned short* __restrict__ dst, int n) {
  int i = (blockIdx.x * 256 + threadIdx.x) * 4;
  if (i >= n) return;
  float4 v = *(const float4*)(src + i);
  ushort4 o;
  o.x = f2bf(v.x); o.y = f2bf(v.y); o.z = f2bf(v.z); o.w = f2bf(v.w);
  *(ushort4*)(dst + i) = o;
}

// swizzled LDS read: row stride 128B, byte ^= (row&7)<<4 (balanced 8-slot)
__device__ __forceinline__ bf16x8 ldsw128(const char* mat, int row, int cb) {
  return *(const bf16x8*)(mat + row * 128 + (cb ^ ((row & 7) << 4)));
}

// ---- 256x256 8-phase GEMM, BK=64, 8 waves (2M x 4N), 512 threads ----
#define PH_SYNC_A() do { __builtin_amdgcn_s_barrier();              \
    asm volatile("s_waitcnt lgkmcnt(0)" ::: "memory");              \
    __builtin_amdgcn_sched_barrier(0); } while (0)
#define PH_SYNC_B() do { __builtin_amdgcn_s_barrier();              \
    __builtin_amdgcn_sched_barrier(0); } while (0)
#define VMC6() asm volatile("s_waitcnt vmcnt(6)" ::: "memory")
#define VMC0() asm volatile("s_waitcnt vmcnt(0)" ::: "memory")

#define QUAD(MH, NH, AF, BF) do {                                   \
    __builtin_amdgcn_s_setprio(1);                                  \
    _Pragma("unroll") for (int mt = 0; mt < 4; ++mt)                \
    _Pragma("unroll") for (int nt = 0; nt < 2; ++nt)                \
    _Pragma("unroll") for (int kk = 0; kk < 2; ++kk)                \
      acc[(MH)*4+mt][(NH)*2+nt] =                                   \
          mfma16(AF[mt][kk], BF[nt][kk], acc[(MH)*4+mt][(NH)*2+nt]);\
    __builtin_amdgcn_s_setprio(0);                                  \
  } while (0)

__device__ __forceinline__ void stage_half(const char* gbase, char* mat,
                                           int kt, int half, int tid) {
#pragma unroll
  for (int q = 0; q < 2; ++q) {
    const int r = half * 128 + q * 64 + (tid >> 3);
    const int cb = (tid & 7) * 16;
    gld16(gbase + (size_t)r * 2048 + kt * 128 + (cb ^ ((r & 7) << 4)),
          mat + r * 128 + cb);
  }
}

__device__ __forceinline__ void rdA(bf16x8 aF[4][2], const char* mat,
                                    int wm, int mh, int lr, int lg) {
#pragma unroll
  for (int mt = 0; mt < 4; ++mt) {
    const int row = mh * 128 + wm * 64 + mt * 16 + lr;
#pragma unroll
    for (int kk = 0; kk < 2; ++kk)
      aF[mt][kk] = ldsw128(mat, row, kk * 64 + lg * 16);
  }
}
__device__ __forceinline__ void rdB(bf16x8 bF[2][2], const char* mat,
                                    int wn, int nh, int lr, int lg) {
#pragma unroll
  for (int nt = 0; nt < 2; ++nt) {
    const int row = wn * 64 + nh * 32 + nt * 16 + lr;
#pragma unroll
    for (int kk = 0; kk < 2; ++kk)
      bF[nt][kk] = ldsw128(mat, row, kk * 64 + lg * 16);
  }
}

template <int MODE>
__global__ __launch_bounds__(512, 2) void gemm8p(
    const unsigned short* __restrict__ A, const unsigned short* __restrict__ Bm,
    unsigned short* __restrict__ qo, unsigned short* __restrict__ ko,
    unsigned short* __restrict__ vo,
    const float* __restrict__ bias, float* __restrict__ fout) {
  __shared__ char lds[131072];
  const int tid = threadIdx.x;
  const int w = tid >> 6, l = tid & 63, lr = l & 15, lg = l >> 4;
  const int wm = w >> 2, wn = w & 3;
  constexpr int GX = (MODE == 0) ? 12 : 4;
  constexpr int NWG = GX * 32;
  const int L = blockIdx.x + blockIdx.y * GX;
  const int logical = (L & 7) * (NWG >> 3) + (L >> 3);   // bijective (NWG%8==0)
  const int m0 = (logical / GX) * 256, n0 = (logical % GX) * 256;
  const char* Ag = (const char*)A + (size_t)m0 * 2048;
  const char* Bg = (const char*)Bm + (size_t)n0 * 2048;
  char* A0 = lds;           char* B0 = lds + 32768;
  char* A1 = lds + 65536;   char* B1 = lds + 98304;

  f32x4 acc[8][4];
  f32x4 zero = {0.f, 0.f, 0.f, 0.f};
#pragma unroll
  for (int i = 0; i < 8; i++)
#pragma unroll
    for (int jj = 0; jj < 4; jj++) acc[i][jj] = zero;

  stage_half(Ag, A0, 0, 0, tid);
  stage_half(Ag, A0, 0, 1, tid);
  stage_half(Bg, B0, 0, 0, tid);
  stage_half(Bg, B0, 0, 1, tid);
  stage_half(Ag, A1, 1, 0, tid);
  stage_half(Bg, B1, 1, 0, tid);
  stage_half(Bg, B1, 1, 1, tid);
  VMC6();
  __builtin_amdgcn_s_barrier();
  __builtin_amdgcn_sched_barrier(0);

  for (int j = 0; j < 8; ++j) {
    const int t0 = 2 * j, t1 = 2 * j + 1;
    const bool more = (j < 7);
    bf16x8 aF[4][2], b0F[2][2], b1F[2][2];

    rdA(aF, A0, wm, 0, lr, lg);
    rdB(b0F, B0, wn, 0, lr, lg);
    stage_half(Ag, A1, t1, 1, tid);
    PH_SYNC_A();
    QUAD(0, 0, aF, b0F);
    PH_SYNC_B();
    rdB(b1F, B0, wn, 1, lr, lg);
    if (more) stage_half(Ag, A0, t0 + 2, 0, tid);
    PH_SYNC_A();
    QUAD(0, 1, aF, b1F);
    PH_SYNC_B();
    rdA(aF, A0, wm, 1, lr, lg);
    if (more) stage_half(Bg, B0, t0 + 2, 0, tid);
    PH_SYNC_A();
    QUAD(1, 1, aF, b1F);
    PH_SYNC_B();
    if (more) stage_half(Bg, B0, t0 + 2, 1, tid);
    PH_SYNC_A();
    QUAD(1, 0, aF, b0F);
    if (more) VMC6(); else VMC0();
    PH_SYNC_B();
    rdA(aF, A1, wm, 0, lr, lg);
    rdB(b0F, B1, wn, 0, lr, lg);
    if (more) stage_half(Ag, A0, t0 + 2, 1, tid);
    PH_SYNC_A();
    QUAD(0, 0, aF, b0F);
    PH_SYNC_B();
    rdB(b1F, B1, wn, 1, lr, lg);
    if (more) stage_half(Ag, A1, t1 + 2, 0, tid);
    PH_SYNC_A();
    QUAD(0, 1, aF, b1F);
    PH_SYNC_B();
    rdA(aF, A1, wm, 1, lr, lg);
    if (more) stage_half(Bg, B1, t1 + 2, 0, tid);
    PH_SYNC_A();
    QUAD(1, 1, aF, b1F);
    PH_SYNC_B();
    if (more) stage_half(Bg, B1, t1 + 2, 1, tid);
    PH_SYNC_A();
    QUAD(1, 0, aF, b0F);
    if (more) VMC6();
    PH_SYNC_B();
  }

#pragma unroll
  for (int mt8 = 0; mt8 < 8; ++mt8) {
    const int mh = mt8 >> 2, mt = mt8 & 3;
#pragma unroll
    for (int nt4 = 0; nt4 < 4; ++nt4) {
      int n = n0 + wn * 64 + nt4 * 16 + lr;
      int mbase = m0 + mh * 128 + wm * 64 + mt * 16 + lg * 4;
      if (MODE == 0) {
        int ty = n >> 10, cc = n & 1023;
        int h = cc >> 6, dd = cc & 63;
        unsigned short* dst = (ty == 0) ? qo : ((ty == 1) ? ko : vo);
        float sc = (ty == 0) ? 0.18033688011111687f : 1.0f;  // (1/8)*log2(e)
#pragma unroll
        for (int i = 0; i < 4; i++) {
          int m = mbase + i;
          int b = m >> 11, tt = m & 2047;
          dst[(((size_t)(b * 16 + h)) * 2048 + tt) * 64 + dd] =
              f2bf(acc[mt8][nt4][i] * sc);
        }
      } else {
        float bv = bias[n];
#pragma unroll
        for (int i = 0; i < 4; i++) {
          int m = mbase + i;
          fout[(size_t)m * 1024 + n] = acc[mt8][nt4][i] + bv;
        }
      }
    }
  }
}

// v [B,H,T,D] -> vt [B,H,D,T]
__global__ __launch_bounds__(256) void transpose_v64(
    const unsigned short* __restrict__ v, unsigned short* __restrict__ vt) {
  __shared__ unsigned short tile[64 * 72];
  int bh = blockIdx.y, t0 = blockIdx.x * 64;
  const unsigned short* vp = v + (size_t)bh * 2048 * 64;
  unsigned short* vtp = vt + (size_t)bh * 64 * 2048;
  int tid = threadIdx.x;
#pragma unroll
  for (int it = 0; it < 2; ++it) {
    int s = tid + it * 256;
    int r = s >> 3, c = (s & 7) * 8;
    *(uint4*)(tile + r * 72 + c) = *(const uint4*)(vp + (size_t)(t0 + r) * 64 + c);
  }
  __syncthreads();
#pragma unroll
  for (int it = 0; it < 2; ++it) {
    int s = tid + it * 256;
    int d = s >> 3, c = (s & 7) * 8;
    unsigned short tmp[8];
#pragma unroll
    for (int j = 0; j < 8; j++) tmp[j] = tile[(c + j) * 72 + d];
    *(uint4*)(vtp + (size_t)d * 2048 + t0 + c) = *(uint4*)tmp;
  }
}

// swizzled LDS read (attn): row stride 128B, byte ^= (row&7)<<4
__device__ __forceinline__ bf16x8 ldsw(const char* base, int row, int cb) {
  return *(const bf16x8*)(base + row * 128 + (cb ^ ((row & 7) << 4)));
}

// Causal flash attention: 4 waves x 64 q-rows (2 MFMA sets/wave;
// qrow_s = q0 + 8*lane + 2*wave + s).  KV tiles of 64, swapped-operand 32x32x16,
// in-register exp2 softmax + defer-max, complementary-pair block order.
// Both q-sets share each K/V LDS fragment read (halves LDS traffic vs 8-wave).
__global__ __launch_bounds__(256, 2) void attn_causal(
    const unsigned short* __restrict__ qg, const unsigned short* __restrict__ kg,
    const unsigned short* __restrict__ vtg, unsigned short* __restrict__ og) {
  __shared__ char lds[32768];   // dbuf: [K 8K | Vt 8K] x2; reused for out bounce
  const int tid = threadIdx.x;
  const int w = tid >> 6, l = tid & 63, lo = l & 31, hi = l >> 5;
  const int bh = blockIdx.x;
  const int qc = (0x31204657u >> (blockIdx.y * 4)) & 7;  // complementary pairs
  const int q0 = qc * 256;
  const int nkv = qc * 4 + 4;
  const int b = bh >> 4, h = bh & 15;
  const char* kpB = (const char*)(kg + (size_t)bh * 131072);
  const char* vpB = (const char*)(vtg + (size_t)bh * 131072);
  const unsigned short* qp = qg + (size_t)bh * 131072;
  const int qrow0 = q0 + 8 * lo + 2 * w;
  const int qrow1 = qrow0 + 1;

  bf16x8 qf0[4], qf1[4];
#pragma unroll
  for (int c = 0; c < 4; ++c) {
    qf0[c] = *(const bf16x8*)(qp + (size_t)qrow0 * 64 + hi * 8 + c * 16);
    qf1[c] = *(const bf16x8*)(qp + (size_t)qrow1 * 64 + hi * 8 + c * 16);
  }

  f32x16 ov0[2], ov1[2];
#pragma unroll
  for (int r = 0; r < 16; ++r) {
    ov0[0][r] = 0.f; ov0[1][r] = 0.f; ov1[0][r] = 0.f; ov1[1][r] = 0.f;
  }
  const f32x16 zz = {0.f, 0.f, 0.f, 0.f, 0.f, 0.f, 0.f, 0.f,
                     0.f, 0.f, 0.f, 0.f, 0.f, 0.f, 0.f, 0.f};
  float m0s = -__builtin_inff(), ls0 = 0.f;
  float m1s = -__builtin_inff(), ls1 = 0.f;

  // staging: 256 threads, 4 gld16 each (K rows srow/srow+32, V rows srow/srow+32)
  const int srow = tid >> 3;
  const int scw = ((tid & 7) * 16) ^ ((srow & 7) << 4);   // same swz for row+32

  {
    char* nb = lds;
    gld16(kpB + (size_t)srow * 128 + scw, nb + tid * 16);
    gld16(kpB + (size_t)(srow + 32) * 128 + scw, nb + 4096 + tid * 16);
    gld16(vpB + (size_t)srow * 4096 + scw, nb + 8192 + tid * 16);
    gld16(vpB + (size_t)(srow + 32) * 4096 + scw, nb + 12288 + tid * 16);
  }
  __syncthreads();

  for (int kt = 0; kt < nkv; ++kt) {
    const int k0 = kt * 64;
    if (kt + 1 < nkv) {
      char* nb = lds + ((kt + 1) & 1) * 16384;
      const char* ks = kpB + (size_t)(k0 + 64) * 128;
      const char* vs = vpB + (size_t)(k0 + 64) * 2;
      gld16(ks + (size_t)srow * 128 + scw, nb + tid * 16);
      gld16(ks + (size_t)(srow + 32) * 128 + scw, nb + 4096 + tid * 16);
      gld16(vs + (size_t)srow * 4096 + scw, nb + 8192 + tid * 16);
      gld16(vs + (size_t)(srow + 32) * 4096 + scw, nb + 12288 + tid * 16);
    }
    const char* Kbuf = lds + (kt & 1) * 16384;
    const char* Vbuf = Kbuf + 8192;

    // S^T = K·Q^T for both q-sets; each K-frag read feeds 2 MFMAs
    f32x16 sv0[2], sv1[2];
    __builtin_amdgcn_s_setprio(1);
#pragma unroll
    for (int c = 0; c < 4; ++c) {
      bf16x8 kf0 = ldsw(Kbuf, lo, hi * 16 + c * 32);
      bf16x8 kf1 = ldsw(Kbuf, 32 + lo, hi * 16 + c * 32);
      if (c == 0) {
        sv0[0] = mfma32(kf0, qf0[0], zz);
        sv0[1] = mfma32(kf1, qf0[0], zz);
        sv1[0] = mfma32(kf0, qf1[0], zz);
        sv1[1] = mfma32(kf1, qf1[0], zz);
      } else {
        sv0[0] = mfma32(kf0, qf0[c], sv0[0]);
        sv0[1] = mfma32(kf1, qf0[c], sv0[1]);
        sv1[0] = mfma32(kf0, qf1[c], sv1[0]);
        sv1[1] = mfma32(kf1, qf1[c], sv1[1]);
      }
    }
    __builtin_amdgcn_s_setprio(0);

    if (kt >= nkv - 4) {   // causal mask (last 4 tiles only)
#pragma unroll
      for (int t = 0; t < 2; ++t)
#pragma unroll
        for (int r = 0; r < 16; ++r) {
          int kgl = k0 + t * 32 + (r & 3) + 8 * (r >> 2) + 4 * hi;
          if (kgl > qrow0) sv0[t][r] = -__builtin_inff();
          if (kgl > qrow1) sv1[t][r] = -__builtin_inff();
        }
    }

    // online softmax per set (max tree + defer-max + exp2)
    auto softmax_set = [&](f32x16 (&sv)[2], f32x16 (&ov)[2], float& mm, float& ls) {
      float mx[16];
#pragma unroll
      for (int i = 0; i < 16; ++i) mx[i] = fmaxf(sv[0][i], sv[1][i]);
#pragma unroll
      for (int s = 8; s > 0; s >>= 1)
#pragma unroll
        for (int i = 0; i < s; ++i) mx[i] = fmaxf(mx[i], mx[i + s]);
      float tm = fmaxf(mx[0], __shfl_xor(mx[0], 32, 64));
      if (!__all(tm <= mm + 8.f)) {
        float nm = fmaxf(fmaxf(mm, tm), -1e30f);
        float f = exp2f(mm - nm);
        mm = nm;
        ls *= f;
#pragma unroll
        for (int r = 0; r < 16; ++r) { ov[0][r] *= f; ov[1][r] *= f; }
      }
      float ps = 0.f;
#pragma unroll
      for (int t = 0; t < 2; ++t)
#pragma unroll
        for (int r = 0; r < 16; ++r) {
          float p = exp2f(sv[t][r] - mm);
          sv[t][r] = p;
          ps += p;
        }
      ls += ps;
    };
    softmax_set(sv0, ov0, m0s, ls0);
    softmax_set(sv1, ov1, m1s, ls1);

    // P -> bf16 B-frags; each V-frag read feeds both sets
    auto mkpc = [&](f32x16 (&sv)[2], int c) -> bf16x8 {
      const int t = c >> 1, rb = (c & 1) * 8;
      unsigned wA = cvtpk(sv[t][rb + 0], sv[t][rb + 1]);
      unsigned wB = cvtpk(sv[t][rb + 2], sv[t][rb + 3]);
      unsigned wC = cvtpk(sv[t][rb + 4], sv[t][rb + 5]);
      unsigned wD = cvtpk(sv[t][rb + 6], sv[t][rb + 7]);
      asm volatile("v_permlane32_swap_b32 %0, %1" : "+v"(wA), "+v"(wC));
      asm volatile("v_permlane32_swap_b32 %0, %1" : "+v"(wB), "+v"(wD));
      union { uint4 u; bf16x8 h; } pc;
      pc.u.x = wA; pc.u.y = wB; pc.u.z = wC; pc.u.w = wD;
      return pc.h;
    };
    __builtin_amdgcn_s_setprio(1);
#pragma unroll
    for (int c = 0; c < 4; ++c) {
      bf16x8 vf0 = ldsw(Vbuf, lo, hi * 16 + c * 32);
      bf16x8 vf1 = ldsw(Vbuf, 32 + lo, hi * 16 + c * 32);
      bf16x8 p0 = mkpc(sv0, c);
      ov0[0] = mfma32(vf0, p0, ov0[0]);
      ov0[1] = mfma32(vf1, p0, ov0[1]);
      bf16x8 p1 = mkpc(sv1, c);
      ov1[0] = mfma32(vf0, p1, ov1[0]);
      ov1[1] = mfma32(vf1, p1, ov1[1]);
    }
    __builtin_amdgcn_s_setprio(0);
    __syncthreads();
  }

  // epilogue: normalize both sets, bounce through LDS (8KB/wave), coalesced stores
  float lt0 = ls0 + __shfl_xor(ls0, 32, 64);
  float lt1 = ls1 + __shfl_xor(ls1, 32, 64);
  float inv0 = 1.0f / lt0, inv1 = 1.0f / lt1;
  char* outl = lds + w * 8192;   // per-wave 8KB: [set][32 q][64 d] bf16
#pragma unroll
  for (int t2 = 0; t2 < 2; ++t2)
#pragma unroll
    for (int rp = 0; rp < 8; ++rp) {
      const int r = rp * 2;
      const int d0 = (r & 3) + 8 * (r >> 2) + 4 * hi + 32 * t2;
      const int boff = lo * 128 + ((d0 * 2) ^ ((lo & 7) << 4));
      *(unsigned*)(outl + boff) = cvtpk(ov0[t2][r] * inv0, ov0[t2][r + 1] * inv0);
      *(unsigned*)(outl + 4096 + boff) = cvtpk(ov1[t2][r] * inv1, ov1[t2][r + 1] * inv1);
    }
  __syncthreads();
#pragma unroll
  for (int s = 0; s < 2; ++s) {
    const int qi = l >> 1, cbb = (l & 1) * 64;
    const int t = q0 + 8 * qi + 2 * w + s;
    unsigned short* gp = og + ((size_t)(b * 2048 + t)) * 1024 + h * 64 + (cbb >> 1);
#pragma unroll
    for (int i = 0; i < 4; ++i) {
      uint4 vdat = *(const uint4*)(outl + s * 4096 + qi * 128 +
                                   ((cbb + i * 16) ^ ((qi & 7) << 4)));
      *(uint4*)(gp + i * 8) = vdat;
    }
  }
}

extern "C" void kernel_launch(void* const* d_in, const int* in_sizes, int n_in,
                              void* d_out, int out_size, void* d_ws, size_t ws_size,
                              hipStream_t stream) {
  const float* x = (const float*)d_in[0];
  const float* Wqkv = (const float*)d_in[1];
  const float* Wout = (const float*)d_in[2];
  const float* bout = (const float*)d_in[3];
  float* out = (float*)d_out;
  char* ws = (char*)d_ws;

  unsigned short* xb = (unsigned short*)(ws);
  unsigned short* wqb = (unsigned short*)(ws + 16777216);
  unsigned short* wob = (unsigned short*)(ws + 23068672);
  unsigned short* qb = (unsigned short*)(ws + 25165824);
  unsigned short* kb = (unsigned short*)(ws + 41943040);
  unsigned short* vb = (unsigned short*)(ws + 58720256);
  unsigned short* vtb = xb;   // x dead after QKV GEMM
  unsigned short* ogb = vb;   // v dead after transpose

  cast_f32_bf16<<<8192, 256, 0, stream>>>(x, xb, 8388608);
  cast_f32_bf16<<<3072, 256, 0, stream>>>(Wqkv, wqb, 3145728);
  cast_f32_bf16<<<1024, 256, 0, stream>>>(Wout, wob, 1048576);

  gemm8p<0><<<dim3(12, 32), 512, 0, stream>>>(xb, wqb, qb, kb, vb, nullptr, nullptr);
  transpose_v64<<<dim3(32, 64), 256, 0, stream>>>(vb, vtb);
  attn_causal<<<dim3(64, 8), 256, 0, stream>>>(qb, kb, vtb, ogb);
  gemm8p<1><<<dim3(4, 32), 512, 0, stream>>>(ogb, wob, nullptr, nullptr, nullptr, bout, out);
}

// Round 9
// 168.996 us; speedup vs baseline: 1.1295x; 1.1295x over previous
//
#include <hip/hip_runtime.h>

// B=4, T=2048, C=1024, H=16, D=64.  M = B*T = 8192.
// cast f32->bf16; 256x256 8-phase QKV GEMM; V transpose; 8-wave 32q/wave 32x32
// swapped-operand causal flash attention (raw v_exp, max3 tree); 8-phase out GEMM.

typedef __attribute__((ext_vector_type(8))) __bf16 bf16x8;
typedef __attribute__((ext_vector_type(4))) float f32x4;
typedef __attribute__((ext_vector_type(16))) float f32x16;

__device__ __forceinline__ unsigned short f2bf(float f) {
  union { float f; unsigned u; } v; v.f = f;
  unsigned r = v.u + 0x7fffu + ((v.u >> 16) & 1u);   // RNE
  return (unsigned short)(r >> 16);
}

__device__ __forceinline__ unsigned cvtpk(float lo, float hi) {
  unsigned r;
  asm("v_cvt_pk_bf16_f32 %0, %1, %2" : "=v"(r) : "v"(lo), "v"(hi));
  return r;
}

// raw v_exp_f32: D = 2^S0, single TRANS inst (exp2f via OCML adds denorm fixups)
__device__ __forceinline__ float fexp2(float x) {
  float r;
  asm("v_exp_f32 %0, %1" : "=v"(r) : "v"(x));
  return r;
}
__device__ __forceinline__ float max3f(float a, float b, float c) {
  return fmaxf(fmaxf(a, b), c);   // clang fuses to v_max3_f32
}

__device__ __forceinline__ void gld16(const void* g, void* l) {
  __builtin_amdgcn_global_load_lds(
      (const __attribute__((address_space(1))) void*)g,
      (__attribute__((address_space(3))) void*)l, 16, 0, 0);
}

__device__ __forceinline__ f32x4 mfma16(bf16x8 a, bf16x8 b, f32x4 c) {
  return __builtin_amdgcn_mfma_f32_16x16x32_bf16(a, b, c, 0, 0, 0);
}
__device__ __forceinline__ f32x16 mfma32(bf16x8 a, bf16x8 b, f32x16 c) {
  return __builtin_amdgcn_mfma_f32_32x32x16_bf16(a, b, c, 0, 0, 0);
}

__global__ __launch_bounds__(256) void cast_f32_bf16(
    const float* __restrict__ src, unsigned short* __restrict__ dst, int n) {
  int i = (blockIdx.x * 256 + threadIdx.x) * 4;
  if (i >= n) return;
  float4 v = *(const float4*)(src + i);
  ushort4 o;
  o.x = f2bf(v.x); o.y = f2bf(v.y); o.z = f2bf(v.z); o.w = f2bf(v.w);
  *(ushort4*)(dst + i) = o;
}

// swizzled LDS read: row stride 128B, byte ^= (row&7)<<4 (balanced 8-slot)
__device__ __forceinline__ bf16x8 ldsw128(const char* mat, int row, int cb) {
  return *(const bf16x8*)(mat + row * 128 + (cb ^ ((row & 7) << 4)));
}

// ---- 256x256 8-phase GEMM, BK=64, 8 waves (2M x 4N), 512 threads ----
#define PH_SYNC_A() do { __builtin_amdgcn_s_barrier();              \
    asm volatile("s_waitcnt lgkmcnt(0)" ::: "memory");              \
    __builtin_amdgcn_sched_barrier(0); } while (0)
#define PH_SYNC_B() do { __builtin_amdgcn_s_barrier();              \
    __builtin_amdgcn_sched_barrier(0); } while (0)
#define VMC6() asm volatile("s_waitcnt vmcnt(6)" ::: "memory")
#define VMC0() asm volatile("s_waitcnt vmcnt(0)" ::: "memory")

#define QUAD(MH, NH, AF, BF) do {                                   \
    __builtin_amdgcn_s_setprio(1);                                  \
    _Pragma("unroll") for (int mt = 0; mt < 4; ++mt)                \
    _Pragma("unroll") for (int nt = 0; nt < 2; ++nt)                \
    _Pragma("unroll") for (int kk = 0; kk < 2; ++kk)                \
      acc[(MH)*4+mt][(NH)*2+nt] =                                   \
          mfma16(AF[mt][kk], BF[nt][kk], acc[(MH)*4+mt][(NH)*2+nt]);\
    __builtin_amdgcn_s_setprio(0);                                  \
  } while (0)

__device__ __forceinline__ void stage_half(const char* gbase, char* mat,
                                           int kt, int half, int tid) {
#pragma unroll
  for (int q = 0; q < 2; ++q) {
    const int r = half * 128 + q * 64 + (tid >> 3);
    const int cb = (tid & 7) * 16;
    gld16(gbase + (size_t)r * 2048 + kt * 128 + (cb ^ ((r & 7) << 4)),
          mat + r * 128 + cb);
  }
}

__device__ __forceinline__ void rdA(bf16x8 aF[4][2], const char* mat,
                                    int wm, int mh, int lr, int lg) {
#pragma unroll
  for (int mt = 0; mt < 4; ++mt) {
    const int row = mh * 128 + wm * 64 + mt * 16 + lr;
#pragma unroll
    for (int kk = 0; kk < 2; ++kk)
      aF[mt][kk] = ldsw128(mat, row, kk * 64 + lg * 16);
  }
}
__device__ __forceinline__ void rdB(bf16x8 bF[2][2], const char* mat,
                                    int wn, int nh, int lr, int lg) {
#pragma unroll
  for (int nt = 0; nt < 2; ++nt) {
    const int row = wn * 64 + nh * 32 + nt * 16 + lr;
#pragma unroll
    for (int kk = 0; kk < 2; ++kk)
      bF[nt][kk] = ldsw128(mat, row, kk * 64 + lg * 16);
  }
}

template <int MODE>
__global__ __launch_bounds__(512, 2) void gemm8p(
    const unsigned short* __restrict__ A, const unsigned short* __restrict__ Bm,
    unsigned short* __restrict__ qo, unsigned short* __restrict__ ko,
    unsigned short* __restrict__ vo,
    const float* __restrict__ bias, float* __restrict__ fout) {
  __shared__ char lds[131072];
  const int tid = threadIdx.x;
  const int w = tid >> 6, l = tid & 63, lr = l & 15, lg = l >> 4;
  const int wm = w >> 2, wn = w & 3;
  constexpr int GX = (MODE == 0) ? 12 : 4;
  constexpr int NWG = GX * 32;
  const int L = blockIdx.x + blockIdx.y * GX;
  const int logical = (L & 7) * (NWG >> 3) + (L >> 3);   // bijective (NWG%8==0)
  const int m0 = (logical / GX) * 256, n0 = (logical % GX) * 256;
  const char* Ag = (const char*)A + (size_t)m0 * 2048;
  const char* Bg = (const char*)Bm + (size_t)n0 * 2048;
  char* A0 = lds;           char* B0 = lds + 32768;
  char* A1 = lds + 65536;   char* B1 = lds + 98304;

  f32x4 acc[8][4];
  f32x4 zero = {0.f, 0.f, 0.f, 0.f};
#pragma unroll
  for (int i = 0; i < 8; i++)
#pragma unroll
    for (int jj = 0; jj < 4; jj++) acc[i][jj] = zero;

  stage_half(Ag, A0, 0, 0, tid);
  stage_half(Ag, A0, 0, 1, tid);
  stage_half(Bg, B0, 0, 0, tid);
  stage_half(Bg, B0, 0, 1, tid);
  stage_half(Ag, A1, 1, 0, tid);
  stage_half(Bg, B1, 1, 0, tid);
  stage_half(Bg, B1, 1, 1, tid);
  VMC6();
  __builtin_amdgcn_s_barrier();
  __builtin_amdgcn_sched_barrier(0);

  for (int j = 0; j < 8; ++j) {
    const int t0 = 2 * j, t1 = 2 * j + 1;
    const bool more = (j < 7);
    bf16x8 aF[4][2], b0F[2][2], b1F[2][2];

    rdA(aF, A0, wm, 0, lr, lg);
    rdB(b0F, B0, wn, 0, lr, lg);
    stage_half(Ag, A1, t1, 1, tid);
    PH_SYNC_A();
    QUAD(0, 0, aF, b0F);
    PH_SYNC_B();
    rdB(b1F, B0, wn, 1, lr, lg);
    if (more) stage_half(Ag, A0, t0 + 2, 0, tid);
    PH_SYNC_A();
    QUAD(0, 1, aF, b1F);
    PH_SYNC_B();
    rdA(aF, A0, wm, 1, lr, lg);
    if (more) stage_half(Bg, B0, t0 + 2, 0, tid);
    PH_SYNC_A();
    QUAD(1, 1, aF, b1F);
    PH_SYNC_B();
    if (more) stage_half(Bg, B0, t0 + 2, 1, tid);
    PH_SYNC_A();
    QUAD(1, 0, aF, b0F);
    if (more) VMC6(); else VMC0();
    PH_SYNC_B();
    rdA(aF, A1, wm, 0, lr, lg);
    rdB(b0F, B1, wn, 0, lr, lg);
    if (more) stage_half(Ag, A0, t0 + 2, 1, tid);
    PH_SYNC_A();
    QUAD(0, 0, aF, b0F);
    PH_SYNC_B();
    rdB(b1F, B1, wn, 1, lr, lg);
    if (more) stage_half(Ag, A1, t1 + 2, 0, tid);
    PH_SYNC_A();
    QUAD(0, 1, aF, b1F);
    PH_SYNC_B();
    rdA(aF, A1, wm, 1, lr, lg);
    if (more) stage_half(Bg, B1, t1 + 2, 0, tid);
    PH_SYNC_A();
    QUAD(1, 1, aF, b1F);
    PH_SYNC_B();
    if (more) stage_half(Bg, B1, t1 + 2, 1, tid);
    PH_SYNC_A();
    QUAD(1, 0, aF, b0F);
    if (more) VMC6();
    PH_SYNC_B();
  }

#pragma unroll
  for (int mt8 = 0; mt8 < 8; ++mt8) {
    const int mh = mt8 >> 2, mt = mt8 & 3;
#pragma unroll
    for (int nt4 = 0; nt4 < 4; ++nt4) {
      int n = n0 + wn * 64 + nt4 * 16 + lr;
      int mbase = m0 + mh * 128 + wm * 64 + mt * 16 + lg * 4;
      if (MODE == 0) {
        int ty = n >> 10, cc = n & 1023;
        int h = cc >> 6, dd = cc & 63;
        unsigned short* dst = (ty == 0) ? qo : ((ty == 1) ? ko : vo);
        float sc = (ty == 0) ? 0.18033688011111687f : 1.0f;  // (1/8)*log2(e)
#pragma unroll
        for (int i = 0; i < 4; i++) {
          int m = mbase + i;
          int b = m >> 11, tt = m & 2047;
          dst[(((size_t)(b * 16 + h)) * 2048 + tt) * 64 + dd] =
              f2bf(acc[mt8][nt4][i] * sc);
        }
      } else {
        float bv = bias[n];
#pragma unroll
        for (int i = 0; i < 4; i++) {
          int m = mbase + i;
          fout[(size_t)m * 1024 + n] = acc[mt8][nt4][i] + bv;
        }
      }
    }
  }
}

// v [B,H,T,D] -> vt [B,H,D,T]
__global__ __launch_bounds__(256) void transpose_v64(
    const unsigned short* __restrict__ v, unsigned short* __restrict__ vt) {
  __shared__ unsigned short tile[64 * 72];
  int bh = blockIdx.y, t0 = blockIdx.x * 64;
  const unsigned short* vp = v + (size_t)bh * 2048 * 64;
  unsigned short* vtp = vt + (size_t)bh * 64 * 2048;
  int tid = threadIdx.x;
#pragma unroll
  for (int it = 0; it < 2; ++it) {
    int s = tid + it * 256;
    int r = s >> 3, c = (s & 7) * 8;
    *(uint4*)(tile + r * 72 + c) = *(const uint4*)(vp + (size_t)(t0 + r) * 64 + c);
  }
  __syncthreads();
#pragma unroll
  for (int it = 0; it < 2; ++it) {
    int s = tid + it * 256;
    int d = s >> 3, c = (s & 7) * 8;
    unsigned short tmp[8];
#pragma unroll
    for (int j = 0; j < 8; j++) tmp[j] = tile[(c + j) * 72 + d];
    *(uint4*)(vtp + (size_t)d * 2048 + t0 + c) = *(uint4*)tmp;
  }
}

// swizzled LDS read (attn): row stride 128B, byte ^= (row&7)<<4
__device__ __forceinline__ bf16x8 ldsw(const char* base, int row, int cb) {
  return *(const bf16x8*)(base + row * 128 + (cb ^ ((row & 7) << 4)));
}

// Causal flash attention, 8 waves x 32 q-rows (strided: q = q0 + 8*lane + w).
// KV tiles of 64, swapped-operand 32x32x16 MFMA, in-register exp2 softmax
// (raw v_exp, max3 tree, 4-way partial sums), defer-max, complementary pairs.
__global__ __launch_bounds__(512, 4) void attn_causal(
    const unsigned short* __restrict__ qg, const unsigned short* __restrict__ kg,
    const unsigned short* __restrict__ vtg, unsigned short* __restrict__ og) {
  __shared__ char lds[32768];   // dbuf: [K 8K | Vt 8K] x2; reused for out bounce
  const int tid = threadIdx.x;
  const int w = tid >> 6, l = tid & 63, lo = l & 31, hi = l >> 5;
  const int bh = blockIdx.x;
  const int qc = (0x31204657u >> (blockIdx.y * 4)) & 7;  // complementary pairs
  const int q0 = qc * 256;
  const int nkv = qc * 4 + 4;
  const int b = bh >> 4, h = bh & 15;
  const char* kpB = (const char*)(kg + (size_t)bh * 131072);
  const char* vpB = (const char*)(vtg + (size_t)bh * 131072);
  const unsigned short* qp = qg + (size_t)bh * 131072;
  const int qrow = q0 + 8 * lo + w;

  bf16x8 qf[4];
#pragma unroll
  for (int c = 0; c < 4; ++c)
    qf[c] = *(const bf16x8*)(qp + (size_t)qrow * 64 + hi * 8 + c * 16);

  f32x16 ov[2];
#pragma unroll
  for (int r = 0; r < 16; ++r) { ov[0][r] = 0.f; ov[1][r] = 0.f; }
  const f32x16 zz = {0.f, 0.f, 0.f, 0.f, 0.f, 0.f, 0.f, 0.f,
                     0.f, 0.f, 0.f, 0.f, 0.f, 0.f, 0.f, 0.f};
  float m = -__builtin_inff(), lsum = 0.f;

  const int srow = tid >> 3;
  const int scb = ((tid & 7) * 16) ^ ((srow & 7) << 4);

  gld16(kpB + (size_t)srow * 128 + scb, lds + tid * 16);
  gld16(vpB + (size_t)srow * 4096 + scb, lds + 8192 + tid * 16);
  __syncthreads();

  for (int kt = 0; kt < nkv; ++kt) {
    const int k0 = kt * 64;
    if (kt + 1 < nkv) {
      char* nb = lds + ((kt + 1) & 1) * 16384;
      gld16(kpB + (size_t)(k0 + 64 + srow) * 128 + scb, nb + tid * 16);
      gld16(vpB + (size_t)srow * 4096 + (size_t)(k0 + 64) * 2 + scb, nb + 8192 + tid * 16);
    }
    const char* Kbuf = lds + (kt & 1) * 16384;
    const char* Vbuf = Kbuf + 8192;

    // S^T = K·Q^T (two 32-row k blocks, 4 d-chunks); first chunk uses zero acc
    f32x16 sv[2];
    __builtin_amdgcn_s_setprio(1);
#pragma unroll
    for (int c = 0; c < 4; ++c) {
      bf16x8 kf0 = ldsw(Kbuf, lo, hi * 16 + c * 32);
      bf16x8 kf1 = ldsw(Kbuf, 32 + lo, hi * 16 + c * 32);
      if (c == 0) {
        sv[0] = mfma32(kf0, qf[0], zz);
        sv[1] = mfma32(kf1, qf[0], zz);
      } else {
        sv[0] = mfma32(kf0, qf[c], sv[0]);
        sv[1] = mfma32(kf1, qf[c], sv[1]);
      }
    }
    __builtin_amdgcn_s_setprio(0);

    if (kt >= nkv - 4) {   // causal mask (last 4 tiles only)
#pragma unroll
      for (int t = 0; t < 2; ++t)
#pragma unroll
        for (int r = 0; r < 16; ++r) {
          int kgl = k0 + t * 32 + (r & 3) + 8 * (r >> 2) + 4 * hi;
          if (kgl > qrow) sv[t][r] = -__builtin_inff();
        }
    }

    // tile max via v_max3 tree: 32 -> 11 -> 4 -> 1  (~17 ops, depth 4)
    float t0m = max3f(sv[0][0], sv[0][1], sv[0][2]);
    float t1m = max3f(sv[0][3], sv[0][4], sv[0][5]);
    float t2m = max3f(sv[0][6], sv[0][7], sv[0][8]);
    float t3m = max3f(sv[0][9], sv[0][10], sv[0][11]);
    float t4m = max3f(sv[0][12], sv[0][13], sv[0][14]);
    float t5m = max3f(sv[0][15], sv[1][0], sv[1][1]);
    float t6m = max3f(sv[1][2], sv[1][3], sv[1][4]);
    float t7m = max3f(sv[1][5], sv[1][6], sv[1][7]);
    float t8m = max3f(sv[1][8], sv[1][9], sv[1][10]);
    float t9m = max3f(sv[1][11], sv[1][12], sv[1][13]);
    float tam = fmaxf(sv[1][14], sv[1][15]);
    float u0 = max3f(t0m, t1m, t2m);
    float u1 = max3f(t3m, t4m, t5m);
    float u2 = max3f(t6m, t7m, t8m);
    float u3 = fmaxf(t9m, tam);
    float tm = fmaxf(max3f(u0, u1, u2), u3);
    tm = fmaxf(tm, __shfl_xor(tm, 32, 64));

    // defer-max: rescale only when the running max grew by >8 (exp2 domain).
    if (!__all(tm <= m + 8.f)) {
      float nm = fmaxf(fmaxf(m, tm), -1e30f);   // clamp: fully-masked lanes stay sane
      float f = fexp2(m - nm);
      m = nm;
      lsum *= f;
#pragma unroll
      for (int r = 0; r < 16; ++r) { ov[0][r] *= f; ov[1][r] *= f; }
    }

    // P = 2^(S-m) via raw v_exp; 4 independent partial sums
    float ps0 = 0.f, ps1 = 0.f, ps2 = 0.f, ps3 = 0.f;
#pragma unroll
    for (int t = 0; t < 2; ++t)
#pragma unroll
      for (int r = 0; r < 16; r += 4) {
        float p0 = fexp2(sv[t][r + 0] - m);
        float p1 = fexp2(sv[t][r + 1] - m);
        float p2 = fexp2(sv[t][r + 2] - m);
        float p3 = fexp2(sv[t][r + 3] - m);
        sv[t][r + 0] = p0; sv[t][r + 1] = p1;
        sv[t][r + 2] = p2; sv[t][r + 3] = p3;
        ps0 += p0; ps1 += p1; ps2 += p2; ps3 += p3;
      }
    lsum += (ps0 + ps1) + (ps2 + ps3);

    // P -> bf16 B-frags (cvt_pk + permlane32_swap), then O^T += Vt·P^T
    __builtin_amdgcn_s_setprio(1);
#pragma unroll
    for (int c = 0; c < 4; ++c) {
      const int t = c >> 1, rb = (c & 1) * 8;
      unsigned wA = cvtpk(sv[t][rb + 0], sv[t][rb + 1]);
      unsigned wB = cvtpk(sv[t][rb + 2], sv[t][rb + 3]);
      unsigned wC = cvtpk(sv[t][rb + 4], sv[t][rb + 5]);
      unsigned wD = cvtpk(sv[t][rb + 6], sv[t][rb + 7]);
      asm volatile("v_permlane32_swap_b32 %0, %1" : "+v"(wA), "+v"(wC));
      asm volatile("v_permlane32_swap_b32 %0, %1" : "+v"(wB), "+v"(wD));
      union { uint4 u; bf16x8 h; } pc;
      pc.u.x = wA; pc.u.y = wB; pc.u.z = wC; pc.u.w = wD;
      bf16x8 vf0 = ldsw(Vbuf, lo, hi * 16 + c * 32);
      bf16x8 vf1 = ldsw(Vbuf, 32 + lo, hi * 16 + c * 32);
      ov[0] = mfma32(vf0, pc.h, ov[0]);
      ov[1] = mfma32(vf1, pc.h, ov[1]);
    }
    __builtin_amdgcn_s_setprio(0);
    __syncthreads();
  }

  // epilogue: normalize, bounce through LDS (swizzled) for coalesced stores
  float lt = lsum + __shfl_xor(lsum, 32, 64);
  float inv = 1.0f / lt;
  char* outl = lds + w * 4096;   // per-wave 4KB region: [32 q][64 d] bf16
#pragma unroll
  for (int t2 = 0; t2 < 2; ++t2)
#pragma unroll
    for (int rp = 0; rp < 8; ++rp) {
      const int r = rp * 2;
      const int d0 = (r & 3) + 8 * (r >> 2) + 4 * hi + 32 * t2;
      unsigned pw = cvtpk(ov[t2][r] * inv, ov[t2][r + 1] * inv);
      *(unsigned*)(outl + lo * 128 + ((d0 * 2) ^ ((lo & 7) << 4))) = pw;
    }
  __syncthreads();
  {
    const int qi = l >> 1, cbb = (l & 1) * 64;
    const int t = q0 + 8 * qi + w;
    unsigned short* gp = og + ((size_t)(b * 2048 + t)) * 1024 + h * 64 + (cbb >> 1);
#pragma unroll
    for (int i = 0; i < 4; ++i) {
      uint4 vdat = *(const uint4*)(outl + qi * 128 + ((cbb + i * 16) ^ ((qi & 7) << 4)));
      *(uint4*)(gp + i * 8) = vdat;
    }
  }
}

extern "C" void kernel_launch(void* const* d_in, const int* in_sizes, int n_in,
                              void* d_out, int out_size, void* d_ws, size_t ws_size,
                              hipStream_t stream) {
  const float* x = (const float*)d_in[0];
  const float* Wqkv = (const float*)d_in[1];
  const float* Wout = (const float*)d_in[2];
  const float* bout = (const float*)d_in[3];
  float* out = (float*)d_out;
  char* ws = (char*)d_ws;

  unsigned short* xb = (unsigned short*)(ws);
  unsigned short* wqb = (unsigned short*)(ws + 16777216);
  unsigned short* wob = (unsigned short*)(ws + 23068672);
  unsigned short* qb = (unsigned short*)(ws + 25165824);
  unsigned short* kb = (unsigned short*)(ws + 41943040);
  unsigned short* vb = (unsigned short*)(ws + 58720256);
  unsigned short* vtb = xb;   // x dead after QKV GEMM
  unsigned short* ogb = vb;   // v dead after transpose

  cast_f32_bf16<<<8192, 256, 0, stream>>>(x, xb, 8388608);
  cast_f32_bf16<<<3072, 256, 0, stream>>>(Wqkv, wqb, 3145728);
  cast_f32_bf16<<<1024, 256, 0, stream>>>(Wout, wob, 1048576);

  gemm8p<0><<<dim3(12, 32), 512, 0, stream>>>(xb, wqb, qb, kb, vb, nullptr, nullptr);
  transpose_v64<<<dim3(32, 64), 256, 0, stream>>>(vb, vtb);
  attn_causal<<<dim3(64, 8), 512, 0, stream>>>(qb, kb, vtb, ogb);
  gemm8p<1><<<dim3(4, 32), 512, 0, stream>>>(ogb, wob, nullptr, nullptr, nullptr, bout, out);
}